// Round 7
// baseline (719.136 us; speedup 1.0000x reference)
//
#include <hip/hip_runtime.h>
#include <hip/hip_bf16.h>

#define NN 50000
#define NE 600000
#define D 128
#define NL 5
#define AGG_BLOCKS 2048
#define M_TILES 391          // (NN+127)/128

typedef __hip_bfloat16 bf16;
typedef unsigned short ushort_t;
typedef _Float16 half_t;
typedef __attribute__((ext_vector_type(8))) _Float16 half8;
typedef __attribute__((ext_vector_type(4))) _Float16 half4;
typedef __attribute__((ext_vector_type(8))) short short8;
typedef __attribute__((ext_vector_type(4))) float f32x4;
typedef __attribute__((ext_vector_type(2))) float f32x2;

__device__ __forceinline__ float b2f(bf16 v) { return __bfloat162float(v); }

__device__ __forceinline__ float loadF(const void* p, long long i, int isf32) {
    if (isf32) return ((const float*)p)[i];
    return b2f(((const bf16*)p)[i]);
}

__global__ void detect_k(const void* __restrict__ atom, int* __restrict__ flag) {
    __shared__ int vote;
    if (threadIdx.x == 0) vote = 0;
    __syncthreads();
    unsigned short u = ((const unsigned short*)atom)[threadIdx.x];
    unsigned short ex = (u >> 7) & 0xFF;
    if (ex >= 0x90) atomicOr(&vote, 1);
    __syncthreads();
    if (threadIdx.x == 0) *flag = vote;
}

__global__ void zero_f(float* __restrict__ p, int n) {
    int i = blockIdx.x * 256 + threadIdx.x;
    if (i < n) p[i] = 0.f;
}
__global__ void zero_i(int* __restrict__ p, int n) {
    int i = blockIdx.x * 256 + threadIdx.x;
    if (i < n) p[i] = 0;
}

// convert + transpose weights to fp16 once per launch; also precompute all
// layers' fused edge-class tables comb[l][c][f] = e1[l][c>>2][f] + e2[l][c&3][f]
__global__ void prepw_k(const void* __restrict__ W1, const void* __restrict__ W2,
                        const void* __restrict__ e1, const void* __restrict__ e2,
                        const int* __restrict__ fl,
                        half_t* __restrict__ w1t, half_t* __restrict__ w2t,
                        float* __restrict__ combT) {
    int isf32 = *fl;
    int idx = blockIdx.x * 256 + threadIdx.x;
    const int per = NL * 2 * D * D;
    if (idx < per) {
        int l = idx / (2 * D * D);
        int r = idx % (2 * D * D);
        int n = r >> 7, k = r & 127;
        w1t[idx] = (half_t)loadF(W1, (long long)l * 2 * D * D + (long long)k * 256 + n, isf32);
    } else if (idx < 2 * per) {
        int j = idx - per;
        int l = j / (2 * D * D);
        int r = j % (2 * D * D);
        int n = r >> 8, k = r & 255;
        w2t[j] = (half_t)loadF(W2, (long long)l * 2 * D * D + (long long)k * D + n, isf32);
    } else if (idx < 2 * per + NL * 24 * D) {
        int j = idx - 2 * per;
        int l = j / (24 * D);
        int r = j % (24 * D);
        int c = r >> 7, f = r & 127;
        combT[j] = loadF(e1, (long long)l * 6 * D + (long long)(c >> 2) * D + f, isf32) +
                   loadF(e2, (long long)l * 4 * D + (long long)(c & 3) * D + f, isf32);
    }
}

// ---------------- CSR build ----------------
__global__ void hist_k(const int* __restrict__ ei, int* __restrict__ deg) {
    int e = blockIdx.x * 256 + threadIdx.x;
    if (e < NE) atomicAdd(&deg[ei[NE + e]], 1);
}

__global__ void scan1_k(const int* __restrict__ deg, int* __restrict__ tmp,
                        int* __restrict__ partial) {
    __shared__ int s[256];
    int t = threadIdx.x;
    int i = blockIdx.x * 256 + t;
    int v = (i < NN) ? deg[i] : 0;
    s[t] = v;
    __syncthreads();
    for (int off = 1; off < 256; off <<= 1) {
        int x = (t >= off) ? s[t - off] : 0;
        __syncthreads();
        s[t] += x;
        __syncthreads();
    }
    if (i < NN) tmp[i] = s[t];
    if (t == 255) partial[blockIdx.x] = s[255];
}

__global__ void scan2_k(int* __restrict__ partial, int nb) {
    __shared__ int s[256];
    int t = threadIdx.x;
    int v = (t < nb) ? partial[t] : 0;
    s[t] = v;
    __syncthreads();
    for (int off = 1; off < 256; off <<= 1) {
        int x = (t >= off) ? s[t - off] : 0;
        __syncthreads();
        s[t] += x;
        __syncthreads();
    }
    int excl = s[t] - v;
    __syncthreads();
    if (t < nb) partial[t] = excl;
}

__global__ void scan3_k(const int* __restrict__ tmp, const int* __restrict__ partial,
                        const int* __restrict__ deg,
                        int* __restrict__ row_start, int* __restrict__ next) {
    int i = blockIdx.x * 256 + threadIdx.x;
    if (i >= NN) return;
    int incl = tmp[i] + partial[i >> 8];
    row_start[i + 1] = incl;
    next[i] = incl - deg[i];
    if (i == 0) row_start[0] = 0;
}

__global__ void fill_k(const int* __restrict__ ei, const int* __restrict__ ea,
                       int* __restrict__ next, int* __restrict__ csr) {
    int e = blockIdx.x * 256 + threadIdx.x;
    if (e >= NE) return;
    int src = ei[e];
    int dst = ei[NE + e];
    int c = ea[2 * e] * 4 + ea[2 * e + 1];
    int pos = atomicAdd(&next[dst], 1);
    csr[pos] = src | (c << 16);
}

// ---------------- forward ----------------
// embedding -> raw fp16 h2 (layer-0 aggr uses identity norm, no relu)
__global__ void embed_k(const int* __restrict__ x,
                        const void* __restrict__ atom,
                        const void* __restrict__ chir,
                        const void* __restrict__ hyb,
                        const int* __restrict__ fl,
                        half_t* __restrict__ h2) {
    int isf32 = *fl;
    int idx = blockIdx.x * 256 + threadIdx.x;   // over NN*64
    if (idx >= NN * 64) return;
    int n = idx >> 6, fp = (idx & 63) * 2;
    long long i0 = (long long)x[n * 3 + 0] * D + fp;
    long long i1 = (long long)x[n * 3 + 1] * D + fp;
    long long i2 = (long long)x[n * 3 + 2] * D + fp;
    float v0 = loadF(atom, i0, isf32) + loadF(chir, i1, isf32) + loadF(hyb, i2, isf32);
    float v1 = loadF(atom, i0 + 1, isf32) + loadF(chir, i1 + 1, isf32) + loadF(hyb, i2 + 1, isf32);
    half_t* dst = h2 + (long long)n * D + fp;
    dst[0] = (half_t)v0;
    dst[1] = (half_t)v1;
}

// in-place BN(layer lprev stats/params) + ReLU over h2.
__global__ void norm_k(half_t* __restrict__ h2,
                       const float* __restrict__ stats,
                       const void* __restrict__ gm, const void* __restrict__ bt,
                       const int* __restrict__ fl, int lprev) {
    __shared__ float norm_s[2 * D];
    int isf32 = *fl;
    int tid = threadIdx.x;
    if (tid < D) {
        float mu = stats[tid] * (1.f / NN);
        float var = fmaxf(stats[D + tid] * (1.f / NN) - mu * mu, 0.f);
        float rs = rsqrtf(var + 1e-5f);
        float sc = rs * loadF(gm, (long long)lprev * D + tid, isf32);
        float sh = loadF(bt, (long long)lprev * D + tid, isf32) - mu * sc;
        norm_s[tid] = sc;
        norm_s[D + tid] = sh;
    }
    __syncthreads();
    int idx = blockIdx.x * 256 + tid;   // over NN*16 (8 fp16 each)
    if (idx >= NN * 16) return;
    int fp = (idx & 15) * 8;
    half_t* p = h2 + (long long)(idx >> 4) * D + fp;
    half8 v = *(half8*)p;
#pragma unroll
    for (int j = 0; j < 8; ++j) {
        float f = fmaxf(fmaf((float)v[j], norm_s[fp + j], norm_s[D + fp + j]), 0.f);
        v[j] = (half_t)f;
    }
    *(half8*)p = v;
}

// grid-stride aggregation, quarter-wave gather (round-5 version, unchanged)
__global__ __launch_bounds__(256) void aggr_k(
        const half_t* __restrict__ h,
        const int* __restrict__ row_start,
        const int* __restrict__ csr,
        const float* __restrict__ combT, int layer,
        half_t* __restrict__ agg) {
    __shared__ float comb[24 * D];
    int tid = threadIdx.x;
    const float* ct = combT + layer * 24 * D;
    for (int i = tid * 4; i < 24 * D; i += 1024)
        *(f32x4*)&comb[i] = *(const f32x4*)(ct + i);
    __syncthreads();
    int lane = tid & 63;
    int qw = lane >> 4;              // quarter id 0..3
    int f8 = (lane & 15) * 8;        // features f8..f8+7
    int wgid = blockIdx.x * 4 + (tid >> 6);
    int n0 = (int)(((long long)wgid * NN) >> 13);
    int n1 = (int)(((long long)(wgid + 1) * NN) >> 13);
    int beg = row_start[n0];
    for (int n = n0; n < n1; ++n) {
        int end = row_start[n + 1];
        float a0[8], a1[8];
#pragma unroll
        for (int j = 0; j < 8; ++j) { a0[j] = 0.f; a1[j] = 0.f; }
        int i = beg;
        for (; i + 7 < end; i += 8) {
            int pk0 = csr[i + qw];
            int pk1 = csr[i + 4 + qw];
            half8 g0 = *(const half8*)(h + (long long)(pk0 & 0xFFFF) * D + f8);
            half8 g1 = *(const half8*)(h + (long long)(pk1 & 0xFFFF) * D + f8);
            const float* c0 = &comb[(pk0 >> 16) * D + f8];
            const float* c1 = &comb[(pk1 >> 16) * D + f8];
#pragma unroll
            for (int j = 0; j < 8; ++j) {
                a0[j] += (float)g0[j] + c0[j];
                a1[j] += (float)g1[j] + c1[j];
            }
        }
        for (; i + 3 < end; i += 4) {
            int pk = csr[i + qw];
            half8 g = *(const half8*)(h + (long long)(pk & 0xFFFF) * D + f8);
            const float* c = &comb[(pk >> 16) * D + f8];
#pragma unroll
            for (int j = 0; j < 8; ++j)
                a0[j] += (float)g[j] + c[j];
        }
        if (i + qw < end) {          // tail: 1-3 edges, predicated per quarter
            int pk = csr[i + qw];
            half8 g = *(const half8*)(h + (long long)(pk & 0xFFFF) * D + f8);
            const float* c = &comb[(pk >> 16) * D + f8];
#pragma unroll
            for (int j = 0; j < 8; ++j)
                a0[j] += (float)g[j] + c[j];
        }
        half8 o;
#pragma unroll
        for (int j = 0; j < 8; ++j) {
            float v = a0[j] + a1[j];
            v += __shfl_down(v, 32, 64);
            v += __shfl_down(v, 16, 64);
            o[j] = (half_t)v;
        }
        if (qw == 0)
            *(half8*)(agg + (long long)n * D + f8) = o;
        beg = end;
    }
}

// Fused MLP, L2-direct weights: 391 blocks x 512 threads, ONLY Ms (18.4KB)
// in LDS -> >=2 blocks/CU (16+ waves) instead of the 1 block/CU the 137KB
// weight staging forced. W1/W2 fragments are read per-MFMA straight from
// global: 256KB of weights is L2-resident (every block reads it), total L2
// traffic ~390MB ~= 11us aggregate at 34.5TB/s. No staging barriers; the Ms
// transpose stays wave-private (in-order per-wave DS + lgkmcnt(0)).
__global__ __launch_bounds__(512, 4) void mlp_k(
        const half_t* __restrict__ agg,
        const half_t* __restrict__ w1t, const half_t* __restrict__ w2t,
        const void* __restrict__ b1, const void* __restrict__ b2,
        const int* __restrict__ fl, int layer,
        half_t* __restrict__ h2,
        float* __restrict__ statsAdd, float* __restrict__ statsZero) {
    __shared__ ushort_t Ms[128 * 72];    // mid chunk [m128][k64+pad8] 18.4 KB
    __shared__ float SS[2 * D];
    int isf32 = *fl;
    int tid = threadIdx.x;
    if (blockIdx.x == 0 && tid < 2 * D) statsZero[tid] = 0.f;
    if (tid < 2 * D) SS[tid] = 0.f;
    int w = tid >> 6, lane = tid & 63;
    int quad = lane >> 4, l16 = lane & 15;
    long long b1off = (long long)layer * 2 * D;
    long long b2off = (long long)layer * D;
    int m0 = blockIdx.x * 128;

    int arow = m0 + w * 16 + l16;
    if (arow >= NN) arow = NN - 1;
    const half_t* ap = agg + (long long)arow * D + quad * 8;
    half8 afrag[4];
#pragma unroll
    for (int kk4 = 0; kk4 < 4; ++kk4)
        afrag[kk4] = *(const half8*)(ap + kk4 * 32);

    const half_t* w1p = w1t + (long long)layer * 256 * 128;
    const half_t* w2p = w2t + (long long)layer * 128 * 256;
    f32x4 acc[8];
#pragma unroll
    for (int t = 0; t < 8; ++t) acc[t] = (f32x4){0.f, 0.f, 0.f, 0.f};

#pragma unroll
    for (int nc = 0; nc < 4; ++nc) {
        f32x4 macc[4];
#pragma unroll
        for (int nt = 0; nt < 4; ++nt) macc[nt] = (f32x4){0.f, 0.f, 0.f, 0.f};
#pragma unroll
        for (int kk4 = 0; kk4 < 4; ++kk4) {
            half8 a = afrag[kk4];
#pragma unroll
            for (int nt = 0; nt < 4; ++nt) {
                half8 b = *(const half8*)(w1p + (long long)(nc * 64 + nt * 16 + l16) * 128 + kk4 * 32 + quad * 8);
                macc[nt] = __builtin_amdgcn_mfma_f32_16x16x32_f16(a, b, macc[nt], 0, 0, 0);
            }
        }
        // bias + relu -> Ms (C-layout -> A-layout; wave-private slice)
#pragma unroll
        for (int nt = 0; nt < 4; ++nt) {
            float bias = loadF(b1, b1off + nc * 64 + nt * 16 + l16, isf32);
#pragma unroll
            for (int r = 0; r < 4; ++r) {
                float v = fmaxf(macc[nt][r] + bias, 0.f);
                half_t hv = (half_t)v;
                Ms[(w * 16 + quad * 4 + r) * 72 + nt * 16 + l16] = *(ushort_t*)&hv;
            }
        }
        // cross-lane within wave: ensure Ms writes landed before reads
        asm volatile("s_waitcnt lgkmcnt(0)" ::: "memory");
#pragma unroll
        for (int kk4 = 0; kk4 < 2; ++kk4) {
            half8 a = *(const half8*)&Ms[(w * 16 + l16) * 72 + kk4 * 32 + quad * 8];
#pragma unroll
            for (int t = 0; t < 8; ++t) {
                half8 b = *(const half8*)(w2p + (long long)((t >> 2) * 64 + (t & 3) * 16 + l16) * 256 + nc * 64 + kk4 * 32 + quad * 8);
                acc[t] = __builtin_amdgcn_mfma_f32_16x16x32_f16(a, b, acc[t], 0, 0, 0);
            }
        }
    }

    float ssum[8], sq[8];
#pragma unroll
    for (int t = 0; t < 8; ++t) { ssum[t] = 0.f; sq[t] = 0.f; }
#pragma unroll
    for (int t = 0; t < 8; ++t) {
        int col = (t >> 2) * 64 + (t & 3) * 16 + l16;
        float bias = loadF(b2, b2off + col, isf32);
#pragma unroll
        for (int r = 0; r < 4; ++r) {
            int row = m0 + w * 16 + quad * 4 + r;
            if (row < NN) {
                float v = acc[t][r] + bias;
                h2[(long long)row * D + col] = (half_t)v;
                ssum[t] += v; sq[t] += v * v;
            }
        }
    }
    // stats: fold quads within wave, then one LDS atomic pass, one global add
#pragma unroll
    for (int t = 0; t < 8; ++t) {
        ssum[t] += __shfl_xor(ssum[t], 16, 64);
        ssum[t] += __shfl_xor(ssum[t], 32, 64);
        sq[t]   += __shfl_xor(sq[t], 16, 64);
        sq[t]   += __shfl_xor(sq[t], 32, 64);
    }
    if (quad == 0) {
#pragma unroll
        for (int t = 0; t < 8; ++t) {
            int col = (t >> 2) * 64 + (t & 3) * 16 + l16;
            atomicAdd(&SS[col], ssum[t]);
            atomicAdd(&SS[D + col], sq[t]);
        }
    }
    __syncthreads();
    if (tid < 2 * D) atomicAdd(&statsAdd[tid], SS[tid]);
}

// final output: out = BN(h2) with gamma/beta of last layer (no relu), f32
__global__ void apply_k(const half_t* __restrict__ h2,
                        const float* __restrict__ statsPrev,
                        const void* __restrict__ gm, const void* __restrict__ bt,
                        const int* __restrict__ fl,
                        float* __restrict__ out) {
    __shared__ float norm_s[2 * D];
    int isf32 = *fl;
    int tid = threadIdx.x;
    if (tid < D) {
        float mu = statsPrev[tid] * (1.f / NN);
        float var = fmaxf(statsPrev[D + tid] * (1.f / NN) - mu * mu, 0.f);
        float rs = rsqrtf(var + 1e-5f);
        float sc = rs * loadF(gm, (long long)(NL - 1) * D + tid, isf32);
        float sh = loadF(bt, (long long)(NL - 1) * D + tid, isf32) - mu * sc;
        norm_s[tid] = sc;
        norm_s[D + tid] = sh;
    }
    __syncthreads();
    int idx = blockIdx.x * 256 + tid;  // over NN*64
    if (idx >= NN * 64) return;
    int fp = (idx & 63) * 2;
    unsigned hv = *(const unsigned*)(h2 + (long long)(idx >> 6) * D + fp);
    float v0 = fmaf((float)((const half_t*)&hv)[0], norm_s[fp], norm_s[D + fp]);
    float v1 = fmaf((float)((const half_t*)&hv)[1], norm_s[fp + 1], norm_s[D + fp + 1]);
    f32x2 o; o.x = v0; o.y = v1;
    *(f32x2*)(out + (long long)(idx >> 6) * D + fp) = o;
}

extern "C" void kernel_launch(void* const* d_in, const int* in_sizes, int n_in,
                              void* d_out, int out_size, void* d_ws, size_t ws_size,
                              hipStream_t stream) {
    const int* x     = (const int*)d_in[0];
    const int* ei    = (const int*)d_in[1];
    const int* ea    = (const int*)d_in[2];
    const void* atom = d_in[3];
    const void* chir = d_in[4];
    const void* hyb  = d_in[5];
    const void* e1   = d_in[6];
    const void* e2   = d_in[7];
    const void* W1   = d_in[8];
    const void* b1   = d_in[9];
    const void* W2   = d_in[10];
    const void* b2   = d_in[11];
    const void* gm   = d_in[12];
    const void* bt   = d_in[13];

    const size_t ND = (size_t)NN * D;

    char* base = (char*)d_ws;
    float* SP0     = (float*)base;            // stats buffer 0 (256 f32)
    float* SP1     = (float*)(base + 1024);   // stats buffer 1
    int*   flag    = (int*)(base + 2048);
    char*  p       = base + 4096;
    half_t* h2     = (half_t*)p;  p += ND * 2;
    half_t* w1t    = (half_t*)p;  p += (size_t)NL * 2 * D * D * 2;
    half_t* w2t    = (half_t*)p;  p += (size_t)NL * 2 * D * D * 2;
    float* combT   = (float*)p;   p += (size_t)NL * 24 * D * 4;
    int* csr       = (int*)p;     p += (size_t)NE * 4;
    int* row_start = (int*)p;     p += (size_t)(NN + 1) * 4 + 12;
    int* deg       = (int*)p;     p += (size_t)NN * 4;
    int* tmp       = (int*)p;     p += (size_t)NN * 4;
    int* next      = (int*)p;     p += (size_t)NN * 4;
    int* partial   = (int*)p;

    half_t* aggf = (half_t*)d_out;  // fp16 agg scratch; dead before apply_k

    const int N2_BLOCKS = (NN * 64 + 255) / 256;  // 12500
    const int NRM_BLOCKS = (NN * 16 + 255) / 256; // 3125
    const int E_BLOCKS  = (NE + 255) / 256;       // 2344
    const int N_BLOCKS  = (NN + 255) / 256;       // 196
    const int PW_BLOCKS = (2 * NL * 2 * D * D + NL * 24 * D + 255) / 256;

    detect_k<<<1, 256, 0, stream>>>(atom, flag);
    prepw_k<<<PW_BLOCKS, 256, 0, stream>>>(W1, W2, e1, e2, flag, w1t, w2t, combT);

    zero_i<<<N_BLOCKS, 256, 0, stream>>>(deg, NN);
    hist_k<<<E_BLOCKS, 256, 0, stream>>>(ei, deg);
    scan1_k<<<N_BLOCKS, 256, 0, stream>>>(deg, tmp, partial);
    scan2_k<<<1, 256, 0, stream>>>(partial, N_BLOCKS);
    scan3_k<<<N_BLOCKS, 256, 0, stream>>>(tmp, partial, deg, row_start, next);
    fill_k<<<E_BLOCKS, 256, 0, stream>>>(ei, ea, next, csr);

    embed_k<<<N2_BLOCKS, 256, 0, stream>>>(x, atom, chir, hyb, flag, h2);
    zero_f<<<2, 256, 0, stream>>>(SP0, 2 * 2 * D);  // zero both stats buffers

    for (int l = 0; l < NL; ++l) {
        float* sPrev = ((l - 1) & 1) ? SP1 : SP0;   // stats of layer l-1 (l>0)
        float* sAdd  = (l & 1) ? SP1 : SP0;
        float* sZero = ((l + 1) & 1) ? SP1 : SP0;
        if (l > 0)
            norm_k<<<NRM_BLOCKS, 256, 0, stream>>>(h2, sPrev, gm, bt, flag, l - 1);
        aggr_k<<<AGG_BLOCKS, 256, 0, stream>>>(h2, row_start, csr, combT, l, aggf);
        mlp_k<<<M_TILES, 512, 0, stream>>>(aggf, w1t, w2t, b1, b2, flag, l,
                                           h2, sAdd, sZero);
    }
    apply_k<<<N2_BLOCKS, 256, 0, stream>>>(h2, SP0, gm, bt, flag, (float*)d_out);
}

// Round 8
// 476.790 us; speedup vs baseline: 1.5083x; 1.5083x over previous
//
#include <hip/hip_runtime.h>
#include <hip/hip_bf16.h>

#define NN 50000
#define NE 600000
#define D 128
#define NL 5
#define AGG_BLOCKS 2048
#define M_TILES 391          // (NN+127)/128
#define MLP_BLOCKS 256

typedef __hip_bfloat16 bf16;
typedef unsigned short ushort_t;
typedef _Float16 half_t;
typedef __attribute__((ext_vector_type(8))) _Float16 half8;
typedef __attribute__((ext_vector_type(4))) _Float16 half4;
typedef __attribute__((ext_vector_type(8))) short short8;
typedef __attribute__((ext_vector_type(4))) float f32x4;
typedef __attribute__((ext_vector_type(2))) float f32x2;

__device__ __forceinline__ float b2f(bf16 v) { return __bfloat162float(v); }

__device__ __forceinline__ float loadF(const void* p, long long i, int isf32) {
    if (isf32) return ((const float*)p)[i];
    return b2f(((const bf16*)p)[i]);
}

// merged: dtype-detect (block 0) + zero stats (block 0) + zero deg (grid)
__global__ void setup_k(const void* __restrict__ atom, int* __restrict__ flag,
                        int* __restrict__ deg, float* __restrict__ SP01) {
    int tid = threadIdx.x;
    if (blockIdx.x == 0) {
        __shared__ int vote;
        if (tid == 0) vote = 0;
        __syncthreads();
        unsigned short u = ((const unsigned short*)atom)[tid];
        if (((u >> 7) & 0xFF) >= 0x90) atomicOr(&vote, 1);
        __syncthreads();
        if (tid == 0) *flag = vote;
        SP01[tid] = 0.f;           // SP0 [0..255]
        SP01[256 + tid] = 0.f;     // SP1 [0..255]
    }
    int i = blockIdx.x * 256 + tid;
    if (i < NN) deg[i] = 0;
}

// convert + transpose weights to fp16 once per launch; also precompute all
// layers' fused edge-class tables comb[l][c][f] = e1[l][c>>2][f] + e2[l][c&3][f]
__global__ void prepw_k(const void* __restrict__ W1, const void* __restrict__ W2,
                        const void* __restrict__ e1, const void* __restrict__ e2,
                        const int* __restrict__ fl,
                        half_t* __restrict__ w1t, half_t* __restrict__ w2t,
                        float* __restrict__ combT) {
    int isf32 = *fl;
    int idx = blockIdx.x * 256 + threadIdx.x;
    const int per = NL * 2 * D * D;
    if (idx < per) {
        int l = idx / (2 * D * D);
        int r = idx % (2 * D * D);
        int n = r >> 7, k = r & 127;
        w1t[idx] = (half_t)loadF(W1, (long long)l * 2 * D * D + (long long)k * 256 + n, isf32);
    } else if (idx < 2 * per) {
        int j = idx - per;
        int l = j / (2 * D * D);
        int r = j % (2 * D * D);
        int n = r >> 8, k = r & 255;
        w2t[j] = (half_t)loadF(W2, (long long)l * 2 * D * D + (long long)k * D + n, isf32);
    } else if (idx < 2 * per + NL * 24 * D) {
        int j = idx - 2 * per;
        int l = j / (24 * D);
        int r = j % (24 * D);
        int c = r >> 7, f = r & 127;
        combT[j] = loadF(e1, (long long)l * 6 * D + (long long)(c >> 2) * D + f, isf32) +
                   loadF(e2, (long long)l * 4 * D + (long long)(c & 3) * D + f, isf32);
    }
}

// ---------------- CSR build ----------------
__global__ void hist_k(const int* __restrict__ ei, int* __restrict__ deg) {
    int e = blockIdx.x * 256 + threadIdx.x;
    if (e < NE) atomicAdd(&deg[ei[NE + e]], 1);
}

__global__ void scan1_k(const int* __restrict__ deg, int* __restrict__ tmp,
                        int* __restrict__ partial) {
    __shared__ int s[256];
    int t = threadIdx.x;
    int i = blockIdx.x * 256 + t;
    int v = (i < NN) ? deg[i] : 0;
    s[t] = v;
    __syncthreads();
    for (int off = 1; off < 256; off <<= 1) {
        int x = (t >= off) ? s[t - off] : 0;
        __syncthreads();
        s[t] += x;
        __syncthreads();
    }
    if (i < NN) tmp[i] = s[t];
    if (t == 255) partial[blockIdx.x] = s[255];
}

__global__ void scan2_k(int* __restrict__ partial, int nb) {
    __shared__ int s[256];
    int t = threadIdx.x;
    int v = (t < nb) ? partial[t] : 0;
    s[t] = v;
    __syncthreads();
    for (int off = 1; off < 256; off <<= 1) {
        int x = (t >= off) ? s[t - off] : 0;
        __syncthreads();
        s[t] += x;
        __syncthreads();
    }
    int excl = s[t] - v;
    __syncthreads();
    if (t < nb) partial[t] = excl;
}

__global__ void scan3_k(const int* __restrict__ tmp, const int* __restrict__ partial,
                        const int* __restrict__ deg,
                        int* __restrict__ row_start, int* __restrict__ next) {
    int i = blockIdx.x * 256 + threadIdx.x;
    if (i >= NN) return;
    int incl = tmp[i] + partial[i >> 8];
    row_start[i + 1] = incl;
    next[i] = incl - deg[i];
    if (i == 0) row_start[0] = 0;
}

__global__ void fill_k(const int* __restrict__ ei, const int* __restrict__ ea,
                       int* __restrict__ next, int* __restrict__ csr) {
    int e = blockIdx.x * 256 + threadIdx.x;
    if (e >= NE) return;
    int src = ei[e];
    int dst = ei[NE + e];
    int c = ea[2 * e] * 4 + ea[2 * e + 1];
    int pos = atomicAdd(&next[dst], 1);
    csr[pos] = src | (c << 16);
}

// ---------------- forward ----------------
// embedding -> raw fp16 h2 (layer-0 aggr uses identity norm, no relu)
__global__ void embed_k(const int* __restrict__ x,
                        const void* __restrict__ atom,
                        const void* __restrict__ chir,
                        const void* __restrict__ hyb,
                        const int* __restrict__ fl,
                        half_t* __restrict__ h2) {
    int isf32 = *fl;
    int idx = blockIdx.x * 256 + threadIdx.x;   // over NN*64
    if (idx >= NN * 64) return;
    int n = idx >> 6, fp = (idx & 63) * 2;
    long long i0 = (long long)x[n * 3 + 0] * D + fp;
    long long i1 = (long long)x[n * 3 + 1] * D + fp;
    long long i2 = (long long)x[n * 3 + 2] * D + fp;
    float v0 = loadF(atom, i0, isf32) + loadF(chir, i1, isf32) + loadF(hyb, i2, isf32);
    float v1 = loadF(atom, i0 + 1, isf32) + loadF(chir, i1 + 1, isf32) + loadF(hyb, i2 + 1, isf32);
    half_t* dst = h2 + (long long)n * D + fp;
    dst[0] = (half_t)v0;
    dst[1] = (half_t)v1;
}

// in-place BN(layer lprev stats/params) + ReLU over h2.
__global__ void norm_k(half_t* __restrict__ h2,
                       const float* __restrict__ stats,
                       const void* __restrict__ gm, const void* __restrict__ bt,
                       const int* __restrict__ fl, int lprev) {
    __shared__ float norm_s[2 * D];
    int isf32 = *fl;
    int tid = threadIdx.x;
    if (tid < D) {
        float mu = stats[tid] * (1.f / NN);
        float var = fmaxf(stats[D + tid] * (1.f / NN) - mu * mu, 0.f);
        float rs = rsqrtf(var + 1e-5f);
        float sc = rs * loadF(gm, (long long)lprev * D + tid, isf32);
        float sh = loadF(bt, (long long)lprev * D + tid, isf32) - mu * sc;
        norm_s[tid] = sc;
        norm_s[D + tid] = sh;
    }
    __syncthreads();
    int idx = blockIdx.x * 256 + tid;   // over NN*16 (8 fp16 each)
    if (idx >= NN * 16) return;
    int fp = (idx & 15) * 8;
    half_t* p = h2 + (long long)(idx >> 4) * D + fp;
    half8 v = *(half8*)p;
#pragma unroll
    for (int j = 0; j < 8; ++j) {
        float f = fmaxf(fmaf((float)v[j], norm_s[fp + j], norm_s[D + fp + j]), 0.f);
        v[j] = (half_t)f;
    }
    *(half8*)p = v;
}

// grid-stride aggregation, quarter-wave gather (best-known version)
__global__ __launch_bounds__(256) void aggr_k(
        const half_t* __restrict__ h,
        const int* __restrict__ row_start,
        const int* __restrict__ csr,
        const float* __restrict__ combT, int layer,
        half_t* __restrict__ agg) {
    __shared__ float comb[24 * D];
    int tid = threadIdx.x;
    const float* ct = combT + layer * 24 * D;
    for (int i = tid * 4; i < 24 * D; i += 1024)
        *(f32x4*)&comb[i] = *(const f32x4*)(ct + i);
    __syncthreads();
    int lane = tid & 63;
    int qw = lane >> 4;              // quarter id 0..3
    int f8 = (lane & 15) * 8;        // features f8..f8+7
    int wgid = blockIdx.x * 4 + (tid >> 6);
    int n0 = (int)(((long long)wgid * NN) >> 13);
    int n1 = (int)(((long long)(wgid + 1) * NN) >> 13);
    int beg = row_start[n0];
    for (int n = n0; n < n1; ++n) {
        int end = row_start[n + 1];
        float a0[8], a1[8];
#pragma unroll
        for (int j = 0; j < 8; ++j) { a0[j] = 0.f; a1[j] = 0.f; }
        int i = beg;
        for (; i + 7 < end; i += 8) {
            int pk0 = csr[i + qw];
            int pk1 = csr[i + 4 + qw];
            half8 g0 = *(const half8*)(h + (long long)(pk0 & 0xFFFF) * D + f8);
            half8 g1 = *(const half8*)(h + (long long)(pk1 & 0xFFFF) * D + f8);
            const float* c0 = &comb[(pk0 >> 16) * D + f8];
            const float* c1 = &comb[(pk1 >> 16) * D + f8];
#pragma unroll
            for (int j = 0; j < 8; ++j) {
                a0[j] += (float)g0[j] + c0[j];
                a1[j] += (float)g1[j] + c1[j];
            }
        }
        for (; i + 3 < end; i += 4) {
            int pk = csr[i + qw];
            half8 g = *(const half8*)(h + (long long)(pk & 0xFFFF) * D + f8);
            const float* c = &comb[(pk >> 16) * D + f8];
#pragma unroll
            for (int j = 0; j < 8; ++j)
                a0[j] += (float)g[j] + c[j];
        }
        if (i + qw < end) {          // tail: 1-3 edges, predicated per quarter
            int pk = csr[i + qw];
            half8 g = *(const half8*)(h + (long long)(pk & 0xFFFF) * D + f8);
            const float* c = &comb[(pk >> 16) * D + f8];
#pragma unroll
            for (int j = 0; j < 8; ++j)
                a0[j] += (float)g[j] + c[j];
        }
        half8 o;
#pragma unroll
        for (int j = 0; j < 8; ++j) {
            float v = a0[j] + a1[j];
            v += __shfl_down(v, 32, 64);
            v += __shfl_down(v, 16, 64);
            o[j] = (half_t)v;
        }
        if (qw == 0)
            *(half8*)(agg + (long long)n * D + f8) = o;
        beg = end;
    }
}

// Persistent fused MLP (restored best structure): 256 blocks x 512 threads,
// full W1+W2 in LDS once, <=2 tiles/block, zero barriers in the tile path
// (Ms transpose is wave-private). New this round: (a) BOTH tiles' afrag
// global loads issued in the prologue before weight staging (vmcnt in-order
// means they land before first use -> tile-1 A-latency fully hidden);
// (b) all 24 bias values hoisted to registers, removing 16 serialized L2
// scalar loads from the nc-loop critical path.
__global__ __launch_bounds__(512) void mlp_k(
        const half_t* __restrict__ agg,
        const half_t* __restrict__ w1t, const half_t* __restrict__ w2t,
        const void* __restrict__ b1, const void* __restrict__ b2,
        const int* __restrict__ fl, int layer,
        half_t* __restrict__ h2,
        float* __restrict__ statsAdd, float* __restrict__ statsZero) {
    __shared__ ushort_t Bs1[256 * 136];  // full W1 [n256][k128+pad8]  69.6 KB
    __shared__ ushort_t Bs2[128 * 264];  // full W2 [n128][k256+pad8]  67.6 KB
    __shared__ ushort_t Ms[128 * 72];    // mid scratch [m128][k64+pad8] 18.4 KB
    int isf32 = *fl;
    int tid = threadIdx.x;
    if (blockIdx.x == 0 && tid < 2 * D) statsZero[tid] = 0.f;

    int w = tid >> 6, lane = tid & 63;
    int quad = lane >> 4, l16 = lane & 15;
    long long b1off = (long long)layer * 2 * D;
    long long b2off = (long long)layer * D;

    // ---- prologue: issue BOTH tiles' A loads + bias loads first ----
    int tile0 = blockIdx.x;
    int tile1 = blockIdx.x + MLP_BLOCKS;
    int has1 = (tile1 < M_TILES);
    int arow0 = tile0 * 128 + w * 16 + l16;
    if (arow0 >= NN) arow0 = NN - 1;
    int arow1 = has1 ? tile1 * 128 + w * 16 + l16 : arow0;
    if (arow1 >= NN) arow1 = NN - 1;
    const half_t* ap0 = agg + (long long)arow0 * D + quad * 8;
    const half_t* ap1 = agg + (long long)arow1 * D + quad * 8;
    half8 af0[4], af1[4];
#pragma unroll
    for (int k = 0; k < 4; ++k) af0[k] = *(const half8*)(ap0 + k * 32);
#pragma unroll
    for (int k = 0; k < 4; ++k) af1[k] = *(const half8*)(ap1 + k * 32);
    float bias1v[4][4];
#pragma unroll
    for (int nc = 0; nc < 4; ++nc)
#pragma unroll
        for (int nt = 0; nt < 4; ++nt)
            bias1v[nc][nt] = loadF(b1, b1off + nc * 64 + nt * 16 + l16, isf32);
    float bias2v[8];
#pragma unroll
    for (int t = 0; t < 8; ++t)
        bias2v[t] = loadF(b2, b2off + (t >> 2) * 64 + (t & 3) * 16 + l16, isf32);

    // ---- stage full W1 + W2 ----
    const half_t* w1p = w1t + (long long)layer * 256 * 128;
    const half_t* w2p = w2t + (long long)layer * 128 * 256;
    for (int i = tid; i < 256 * 8; i += 512) {
        int r = i >> 3, kq = (i & 7) * 16;
        const ushort_t* src = (const ushort_t*)w1p + r * 128 + kq;
        ushort_t* dst = &Bs1[r * 136 + kq];
        *(short8*)dst = *(const short8*)src;
        *(short8*)(dst + 8) = *(const short8*)(src + 8);
    }
    for (int i = tid; i < 128 * 16; i += 512) {
        int r = i >> 4, kq = (i & 15) * 16;
        const ushort_t* src = (const ushort_t*)w2p + r * 256 + kq;
        ushort_t* dst = &Bs2[r * 264 + kq];
        *(short8*)dst = *(const short8*)src;
        *(short8*)(dst + 8) = *(const short8*)(src + 8);
    }
    __syncthreads();  // weights staged — only barrier before epilogue

    float ssum[8], sq[8];
#pragma unroll
    for (int t = 0; t < 8; ++t) { ssum[t] = 0.f; sq[t] = 0.f; }

    auto process = [&](const half8 (&afrag)[4], int m0) {
        f32x4 acc[8];
#pragma unroll
        for (int t = 0; t < 8; ++t) acc[t] = (f32x4){0.f, 0.f, 0.f, 0.f};
#pragma unroll
        for (int nc = 0; nc < 4; ++nc) {
            f32x4 macc[4];
#pragma unroll
            for (int nt = 0; nt < 4; ++nt) macc[nt] = (f32x4){0.f, 0.f, 0.f, 0.f};
#pragma unroll
            for (int kk4 = 0; kk4 < 4; ++kk4) {
                half8 a = afrag[kk4];
#pragma unroll
                for (int nt = 0; nt < 4; ++nt) {
                    half8 b = *(const half8*)&Bs1[(nc * 64 + nt * 16 + l16) * 136 + kk4 * 32 + quad * 8];
                    macc[nt] = __builtin_amdgcn_mfma_f32_16x16x32_f16(a, b, macc[nt], 0, 0, 0);
                }
            }
#pragma unroll
            for (int nt = 0; nt < 4; ++nt) {
                float bias = bias1v[nc][nt];
#pragma unroll
                for (int r = 0; r < 4; ++r) {
                    float v = fmaxf(macc[nt][r] + bias, 0.f);
                    half_t hv = (half_t)v;
                    Ms[(w * 16 + quad * 4 + r) * 72 + nt * 16 + l16] = *(ushort_t*)&hv;
                }
            }
            asm volatile("s_waitcnt lgkmcnt(0)" ::: "memory");
#pragma unroll
            for (int kk4 = 0; kk4 < 2; ++kk4) {
                half8 a = *(const half8*)&Ms[(w * 16 + l16) * 72 + kk4 * 32 + quad * 8];
#pragma unroll
                for (int t = 0; t < 8; ++t) {
                    half8 b = *(const half8*)&Bs2[((t >> 2) * 64 + (t & 3) * 16 + l16) * 264 + nc * 64 + kk4 * 32 + quad * 8];
                    acc[t] = __builtin_amdgcn_mfma_f32_16x16x32_f16(a, b, acc[t], 0, 0, 0);
                }
            }
        }
#pragma unroll
        for (int t = 0; t < 8; ++t) {
            int col = (t >> 2) * 64 + (t & 3) * 16 + l16;
            float bias = bias2v[t];
#pragma unroll
            for (int r = 0; r < 4; ++r) {
                int row = m0 + w * 16 + quad * 4 + r;
                if (row < NN) {
                    float v = acc[t][r] + bias;
                    h2[(long long)row * D + col] = (half_t)v;
                    ssum[t] += v; sq[t] += v * v;
                }
            }
        }
    };

    process(af0, tile0 * 128);
    if (has1) process(af1, tile1 * 128);

    // stats reduction: fold quads within wave, then one LDS pass per block
#pragma unroll
    for (int t = 0; t < 8; ++t) {
        ssum[t] += __shfl_xor(ssum[t], 16, 64);
        ssum[t] += __shfl_xor(ssum[t], 32, 64);
        sq[t]   += __shfl_xor(sq[t], 16, 64);
        sq[t]   += __shfl_xor(sq[t], 32, 64);
    }
    __syncthreads();                 // all waves done with Ms
    float* SSf = (float*)Ms;         // reuse Ms as 256-float scratch
    if (tid < 2 * D) SSf[tid] = 0.f;
    __syncthreads();
    if (quad == 0) {
#pragma unroll
        for (int t = 0; t < 8; ++t) {
            int col = (t >> 2) * 64 + (t & 3) * 16 + l16;
            atomicAdd(&SSf[col], ssum[t]);
            atomicAdd(&SSf[D + col], sq[t]);
        }
    }
    __syncthreads();
    if (tid < 2 * D) atomicAdd(&statsAdd[tid], SSf[tid]);
}

// final output: out = BN(h2) with gamma/beta of last layer (no relu), f32
__global__ void apply_k(const half_t* __restrict__ h2,
                        const float* __restrict__ statsPrev,
                        const void* __restrict__ gm, const void* __restrict__ bt,
                        const int* __restrict__ fl,
                        float* __restrict__ out) {
    __shared__ float norm_s[2 * D];
    int isf32 = *fl;
    int tid = threadIdx.x;
    if (tid < D) {
        float mu = statsPrev[tid] * (1.f / NN);
        float var = fmaxf(statsPrev[D + tid] * (1.f / NN) - mu * mu, 0.f);
        float rs = rsqrtf(var + 1e-5f);
        float sc = rs * loadF(gm, (long long)(NL - 1) * D + tid, isf32);
        float sh = loadF(bt, (long long)(NL - 1) * D + tid, isf32) - mu * sc;
        norm_s[tid] = sc;
        norm_s[D + tid] = sh;
    }
    __syncthreads();
    int idx = blockIdx.x * 256 + tid;  // over NN*64
    if (idx >= NN * 64) return;
    int fp = (idx & 63) * 2;
    unsigned hv = *(const unsigned*)(h2 + (long long)(idx >> 6) * D + fp);
    float v0 = fmaf((float)((const half_t*)&hv)[0], norm_s[fp], norm_s[D + fp]);
    float v1 = fmaf((float)((const half_t*)&hv)[1], norm_s[fp + 1], norm_s[D + fp + 1]);
    f32x2 o; o.x = v0; o.y = v1;
    *(f32x2*)(out + (long long)(idx >> 6) * D + fp) = o;
}

extern "C" void kernel_launch(void* const* d_in, const int* in_sizes, int n_in,
                              void* d_out, int out_size, void* d_ws, size_t ws_size,
                              hipStream_t stream) {
    const int* x     = (const int*)d_in[0];
    const int* ei    = (const int*)d_in[1];
    const int* ea    = (const int*)d_in[2];
    const void* atom = d_in[3];
    const void* chir = d_in[4];
    const void* hyb  = d_in[5];
    const void* e1   = d_in[6];
    const void* e2   = d_in[7];
    const void* W1   = d_in[8];
    const void* b1   = d_in[9];
    const void* W2   = d_in[10];
    const void* b2   = d_in[11];
    const void* gm   = d_in[12];
    const void* bt   = d_in[13];

    const size_t ND = (size_t)NN * D;

    char* base = (char*)d_ws;
    float* SP0     = (float*)base;            // stats buffer 0 (256 f32)
    float* SP1     = (float*)(base + 1024);   // stats buffer 1
    int*   flag    = (int*)(base + 2048);
    char*  p       = base + 4096;
    half_t* h2     = (half_t*)p;  p += ND * 2;
    half_t* w1t    = (half_t*)p;  p += (size_t)NL * 2 * D * D * 2;
    half_t* w2t    = (half_t*)p;  p += (size_t)NL * 2 * D * D * 2;
    float* combT   = (float*)p;   p += (size_t)NL * 24 * D * 4;
    int* csr       = (int*)p;     p += (size_t)NE * 4;
    int* row_start = (int*)p;     p += (size_t)(NN + 1) * 4 + 12;
    int* deg       = (int*)p;     p += (size_t)NN * 4;
    int* tmp       = (int*)p;     p += (size_t)NN * 4;
    int* next      = (int*)p;     p += (size_t)NN * 4;
    int* partial   = (int*)p;

    half_t* aggf = (half_t*)d_out;  // fp16 agg scratch; dead before apply_k

    const int N2_BLOCKS = (NN * 64 + 255) / 256;  // 12500
    const int NRM_BLOCKS = (NN * 16 + 255) / 256; // 3125
    const int E_BLOCKS  = (NE + 255) / 256;       // 2344
    const int N_BLOCKS  = (NN + 255) / 256;       // 196
    const int PW_BLOCKS = (2 * NL * 2 * D * D + NL * 24 * D + 255) / 256;

    setup_k<<<N_BLOCKS, 256, 0, stream>>>(atom, flag, deg, SP0);
    prepw_k<<<PW_BLOCKS, 256, 0, stream>>>(W1, W2, e1, e2, flag, w1t, w2t, combT);

    hist_k<<<E_BLOCKS, 256, 0, stream>>>(ei, deg);
    scan1_k<<<N_BLOCKS, 256, 0, stream>>>(deg, tmp, partial);
    scan2_k<<<1, 256, 0, stream>>>(partial, N_BLOCKS);
    scan3_k<<<N_BLOCKS, 256, 0, stream>>>(tmp, partial, deg, row_start, next);
    fill_k<<<E_BLOCKS, 256, 0, stream>>>(ei, ea, next, csr);

    embed_k<<<N2_BLOCKS, 256, 0, stream>>>(x, atom, chir, hyb, flag, h2);

    for (int l = 0; l < NL; ++l) {
        float* sPrev = ((l - 1) & 1) ? SP1 : SP0;   // stats of layer l-1 (l>0)
        float* sAdd  = (l & 1) ? SP1 : SP0;
        float* sZero = ((l + 1) & 1) ? SP1 : SP0;
        if (l > 0)
            norm_k<<<NRM_BLOCKS, 256, 0, stream>>>(h2, sPrev, gm, bt, flag, l - 1);
        aggr_k<<<AGG_BLOCKS, 256, 0, stream>>>(h2, row_start, csr, combT, l, aggf);
        mlp_k<<<MLP_BLOCKS, 512, 0, stream>>>(aggf, w1t, w2t, b1, b2, flag, l,
                                              h2, sAdd, sZero);
    }
    apply_k<<<N2_BLOCKS, 256, 0, stream>>>(h2, SP0, gm, bt, flag, (float*)d_out);
}

// Round 9
// 476.522 us; speedup vs baseline: 1.5091x; 1.0006x over previous
//
#include <hip/hip_runtime.h>
#include <hip/hip_bf16.h>

#define NN 50000
#define NE 600000
#define D 128
#define NL 5
#define AGG_BLOCKS 2048
#define M_TILES 391          // (NN+127)/128
#define MLP_BLOCKS 256

typedef __hip_bfloat16 bf16;
typedef unsigned short ushort_t;
typedef _Float16 half_t;
typedef __attribute__((ext_vector_type(8))) _Float16 half8;
typedef __attribute__((ext_vector_type(4))) _Float16 half4;
typedef __attribute__((ext_vector_type(8))) short short8;
typedef __attribute__((ext_vector_type(4))) float f32x4;
typedef __attribute__((ext_vector_type(2))) float f32x2;

__device__ __forceinline__ float b2f(bf16 v) { return __bfloat162float(v); }

__device__ __forceinline__ float loadF(const void* p, long long i, int isf32) {
    if (isf32) return ((const float*)p)[i];
    return b2f(((const bf16*)p)[i]);
}

// merged: dtype-detect (block 0) + zero stats (block 0) + zero deg (grid)
__global__ void setup_k(const void* __restrict__ atom, int* __restrict__ flag,
                        int* __restrict__ deg, float* __restrict__ SP01) {
    int tid = threadIdx.x;
    if (blockIdx.x == 0) {
        __shared__ int vote;
        if (tid == 0) vote = 0;
        __syncthreads();
        unsigned short u = ((const unsigned short*)atom)[tid];
        if (((u >> 7) & 0xFF) >= 0x90) atomicOr(&vote, 1);
        __syncthreads();
        if (tid == 0) *flag = vote;
        SP01[tid] = 0.f;           // SP0 [0..255]
        SP01[256 + tid] = 0.f;     // SP1 [0..255]
    }
    int i = blockIdx.x * 256 + tid;
    if (i < NN) deg[i] = 0;
}

// convert + transpose weights to fp16 once per launch; also precompute all
// layers' fused edge-class tables comb[l][c][f] = e1[l][c>>2][f] + e2[l][c&3][f]
__global__ void prepw_k(const void* __restrict__ W1, const void* __restrict__ W2,
                        const void* __restrict__ e1, const void* __restrict__ e2,
                        const int* __restrict__ fl,
                        half_t* __restrict__ w1t, half_t* __restrict__ w2t,
                        float* __restrict__ combT) {
    int isf32 = *fl;
    int idx = blockIdx.x * 256 + threadIdx.x;
    const int per = NL * 2 * D * D;
    if (idx < per) {
        int l = idx / (2 * D * D);
        int r = idx % (2 * D * D);
        int n = r >> 7, k = r & 127;
        w1t[idx] = (half_t)loadF(W1, (long long)l * 2 * D * D + (long long)k * 256 + n, isf32);
    } else if (idx < 2 * per) {
        int j = idx - per;
        int l = j / (2 * D * D);
        int r = j % (2 * D * D);
        int n = r >> 8, k = r & 255;
        w2t[j] = (half_t)loadF(W2, (long long)l * 2 * D * D + (long long)k * D + n, isf32);
    } else if (idx < 2 * per + NL * 24 * D) {
        int j = idx - 2 * per;
        int l = j / (24 * D);
        int r = j % (24 * D);
        int c = r >> 7, f = r & 127;
        combT[j] = loadF(e1, (long long)l * 6 * D + (long long)(c >> 2) * D + f, isf32) +
                   loadF(e2, (long long)l * 4 * D + (long long)(c & 3) * D + f, isf32);
    }
}

// ---------------- CSR build ----------------
__global__ void hist_k(const int* __restrict__ ei, int* __restrict__ deg) {
    int e = blockIdx.x * 256 + threadIdx.x;
    if (e < NE) atomicAdd(&deg[ei[NE + e]], 1);
}

__global__ void scan1_k(const int* __restrict__ deg, int* __restrict__ tmp,
                        int* __restrict__ partial) {
    __shared__ int s[256];
    int t = threadIdx.x;
    int i = blockIdx.x * 256 + t;
    int v = (i < NN) ? deg[i] : 0;
    s[t] = v;
    __syncthreads();
    for (int off = 1; off < 256; off <<= 1) {
        int x = (t >= off) ? s[t - off] : 0;
        __syncthreads();
        s[t] += x;
        __syncthreads();
    }
    if (i < NN) tmp[i] = s[t];
    if (t == 255) partial[blockIdx.x] = s[255];
}

__global__ void scan2_k(int* __restrict__ partial, int nb) {
    __shared__ int s[256];
    int t = threadIdx.x;
    int v = (t < nb) ? partial[t] : 0;
    s[t] = v;
    __syncthreads();
    for (int off = 1; off < 256; off <<= 1) {
        int x = (t >= off) ? s[t - off] : 0;
        __syncthreads();
        s[t] += x;
        __syncthreads();
    }
    int excl = s[t] - v;
    __syncthreads();
    if (t < nb) partial[t] = excl;
}

__global__ void scan3_k(const int* __restrict__ tmp, const int* __restrict__ partial,
                        const int* __restrict__ deg,
                        int* __restrict__ row_start, int* __restrict__ next) {
    int i = blockIdx.x * 256 + threadIdx.x;
    if (i >= NN) return;
    int incl = tmp[i] + partial[i >> 8];
    row_start[i + 1] = incl;
    next[i] = incl - deg[i];
    if (i == 0) row_start[0] = 0;
}

__global__ void fill_k(const int* __restrict__ ei, const int* __restrict__ ea,
                       int* __restrict__ next, int* __restrict__ csr) {
    int e = blockIdx.x * 256 + threadIdx.x;
    if (e >= NE) return;
    int src = ei[e];
    int dst = ei[NE + e];
    int c = ea[2 * e] * 4 + ea[2 * e + 1];
    int pos = atomicAdd(&next[dst], 1);
    csr[pos] = src | (c << 16);
}

// ---------------- forward ----------------
// embedding -> raw fp16 h2 (layer-0 aggr uses identity norm, no relu)
__global__ void embed_k(const int* __restrict__ x,
                        const void* __restrict__ atom,
                        const void* __restrict__ chir,
                        const void* __restrict__ hyb,
                        const int* __restrict__ fl,
                        half_t* __restrict__ h2) {
    int isf32 = *fl;
    int idx = blockIdx.x * 256 + threadIdx.x;   // over NN*64
    if (idx >= NN * 64) return;
    int n = idx >> 6, fp = (idx & 63) * 2;
    long long i0 = (long long)x[n * 3 + 0] * D + fp;
    long long i1 = (long long)x[n * 3 + 1] * D + fp;
    long long i2 = (long long)x[n * 3 + 2] * D + fp;
    float v0 = loadF(atom, i0, isf32) + loadF(chir, i1, isf32) + loadF(hyb, i2, isf32);
    float v1 = loadF(atom, i0 + 1, isf32) + loadF(chir, i1 + 1, isf32) + loadF(hyb, i2 + 1, isf32);
    half_t* dst = h2 + (long long)n * D + fp;
    dst[0] = (half_t)v0;
    dst[1] = (half_t)v1;
}

// in-place BN(layer lprev stats/params) + ReLU over h2.
__global__ void norm_k(half_t* __restrict__ h2,
                       const float* __restrict__ stats,
                       const void* __restrict__ gm, const void* __restrict__ bt,
                       const int* __restrict__ fl, int lprev) {
    __shared__ float norm_s[2 * D];
    int isf32 = *fl;
    int tid = threadIdx.x;
    if (tid < D) {
        float mu = stats[tid] * (1.f / NN);
        float var = fmaxf(stats[D + tid] * (1.f / NN) - mu * mu, 0.f);
        float rs = rsqrtf(var + 1e-5f);
        float sc = rs * loadF(gm, (long long)lprev * D + tid, isf32);
        float sh = loadF(bt, (long long)lprev * D + tid, isf32) - mu * sc;
        norm_s[tid] = sc;
        norm_s[D + tid] = sh;
    }
    __syncthreads();
    int idx = blockIdx.x * 256 + tid;   // over NN*16 (8 fp16 each)
    if (idx >= NN * 16) return;
    int fp = (idx & 15) * 8;
    half_t* p = h2 + (long long)(idx >> 4) * D + fp;
    half8 v = *(half8*)p;
#pragma unroll
    for (int j = 0; j < 8; ++j) {
        float f = fmaxf(fmaf((float)v[j], norm_s[fp + j], norm_s[D + fp + j]), 0.f);
        v[j] = (half_t)f;
    }
    *(half8*)p = v;
}

// grid-stride aggregation, quarter-wave gather (best-known version)
__global__ __launch_bounds__(256) void aggr_k(
        const half_t* __restrict__ h,
        const int* __restrict__ row_start,
        const int* __restrict__ csr,
        const float* __restrict__ combT, int layer,
        half_t* __restrict__ agg) {
    __shared__ float comb[24 * D];
    int tid = threadIdx.x;
    const float* ct = combT + layer * 24 * D;
    for (int i = tid * 4; i < 24 * D; i += 1024)
        *(f32x4*)&comb[i] = *(const f32x4*)(ct + i);
    __syncthreads();
    int lane = tid & 63;
    int qw = lane >> 4;              // quarter id 0..3
    int f8 = (lane & 15) * 8;        // features f8..f8+7
    int wgid = blockIdx.x * 4 + (tid >> 6);
    int n0 = (int)(((long long)wgid * NN) >> 13);
    int n1 = (int)(((long long)(wgid + 1) * NN) >> 13);
    int beg = row_start[n0];
    for (int n = n0; n < n1; ++n) {
        int end = row_start[n + 1];
        float a0[8], a1[8];
#pragma unroll
        for (int j = 0; j < 8; ++j) { a0[j] = 0.f; a1[j] = 0.f; }
        int i = beg;
        for (; i + 7 < end; i += 8) {
            int pk0 = csr[i + qw];
            int pk1 = csr[i + 4 + qw];
            half8 g0 = *(const half8*)(h + (long long)(pk0 & 0xFFFF) * D + f8);
            half8 g1 = *(const half8*)(h + (long long)(pk1 & 0xFFFF) * D + f8);
            const float* c0 = &comb[(pk0 >> 16) * D + f8];
            const float* c1 = &comb[(pk1 >> 16) * D + f8];
#pragma unroll
            for (int j = 0; j < 8; ++j) {
                a0[j] += (float)g0[j] + c0[j];
                a1[j] += (float)g1[j] + c1[j];
            }
        }
        for (; i + 3 < end; i += 4) {
            int pk = csr[i + qw];
            half8 g = *(const half8*)(h + (long long)(pk & 0xFFFF) * D + f8);
            const float* c = &comb[(pk >> 16) * D + f8];
#pragma unroll
            for (int j = 0; j < 8; ++j)
                a0[j] += (float)g[j] + c[j];
        }
        if (i + qw < end) {          // tail: 1-3 edges, predicated per quarter
            int pk = csr[i + qw];
            half8 g = *(const half8*)(h + (long long)(pk & 0xFFFF) * D + f8);
            const float* c = &comb[(pk >> 16) * D + f8];
#pragma unroll
            for (int j = 0; j < 8; ++j)
                a0[j] += (float)g[j] + c[j];
        }
        half8 o;
#pragma unroll
        for (int j = 0; j < 8; ++j) {
            float v = a0[j] + a1[j];
            v += __shfl_down(v, 32, 64);
            v += __shfl_down(v, 16, 64);
            o[j] = (half_t)v;
        }
        if (qw == 0)
            *(half8*)(agg + (long long)n * D + f8) = o;
        beg = end;
    }
}

// Persistent fused MLP (round-8 winner + coalesced epilogue): the old h2
// store wrote C-fragments directly -> 32 scalar 2B stores/thread (scattered
// 32B granules). Now the biased C values transit the idle Ms buffer
// (wave-private rows, no barrier) and each lane stores contiguous half8
// (16B) segments -> 4 vector stores/thread, 64B-aligned. Two 64-col passes
// reuse the 18.4KB Ms. Stats computed from acc before the transpose.
__global__ __launch_bounds__(512) void mlp_k(
        const half_t* __restrict__ agg,
        const half_t* __restrict__ w1t, const half_t* __restrict__ w2t,
        const void* __restrict__ b1, const void* __restrict__ b2,
        const int* __restrict__ fl, int layer,
        half_t* __restrict__ h2,
        float* __restrict__ statsAdd, float* __restrict__ statsZero) {
    __shared__ ushort_t Bs1[256 * 136];  // full W1 [n256][k128+pad8]  69.6 KB
    __shared__ ushort_t Bs2[128 * 264];  // full W2 [n128][k256+pad8]  67.6 KB
    __shared__ ushort_t Ms[128 * 72];    // mid scratch [m128][k64+pad8] 18.4 KB
    int isf32 = *fl;
    int tid = threadIdx.x;
    if (blockIdx.x == 0 && tid < 2 * D) statsZero[tid] = 0.f;

    int w = tid >> 6, lane = tid & 63;
    int quad = lane >> 4, l16 = lane & 15;
    long long b1off = (long long)layer * 2 * D;
    long long b2off = (long long)layer * D;

    // ---- prologue: issue BOTH tiles' A loads + bias loads first ----
    int tile0 = blockIdx.x;
    int tile1 = blockIdx.x + MLP_BLOCKS;
    int has1 = (tile1 < M_TILES);
    int arow0 = tile0 * 128 + w * 16 + l16;
    if (arow0 >= NN) arow0 = NN - 1;
    int arow1 = has1 ? tile1 * 128 + w * 16 + l16 : arow0;
    if (arow1 >= NN) arow1 = NN - 1;
    const half_t* ap0 = agg + (long long)arow0 * D + quad * 8;
    const half_t* ap1 = agg + (long long)arow1 * D + quad * 8;
    half8 af0[4], af1[4];
#pragma unroll
    for (int k = 0; k < 4; ++k) af0[k] = *(const half8*)(ap0 + k * 32);
#pragma unroll
    for (int k = 0; k < 4; ++k) af1[k] = *(const half8*)(ap1 + k * 32);
    float bias1v[4][4];
#pragma unroll
    for (int nc = 0; nc < 4; ++nc)
#pragma unroll
        for (int nt = 0; nt < 4; ++nt)
            bias1v[nc][nt] = loadF(b1, b1off + nc * 64 + nt * 16 + l16, isf32);
    float bias2v[8];
#pragma unroll
    for (int t = 0; t < 8; ++t)
        bias2v[t] = loadF(b2, b2off + (t >> 2) * 64 + (t & 3) * 16 + l16, isf32);

    // ---- stage full W1 + W2 ----
    const half_t* w1p = w1t + (long long)layer * 256 * 128;
    const half_t* w2p = w2t + (long long)layer * 128 * 256;
    for (int i = tid; i < 256 * 8; i += 512) {
        int r = i >> 3, kq = (i & 7) * 16;
        const ushort_t* src = (const ushort_t*)w1p + r * 128 + kq;
        ushort_t* dst = &Bs1[r * 136 + kq];
        *(short8*)dst = *(const short8*)src;
        *(short8*)(dst + 8) = *(const short8*)(src + 8);
    }
    for (int i = tid; i < 128 * 16; i += 512) {
        int r = i >> 4, kq = (i & 15) * 16;
        const ushort_t* src = (const ushort_t*)w2p + r * 256 + kq;
        ushort_t* dst = &Bs2[r * 264 + kq];
        *(short8*)dst = *(const short8*)src;
        *(short8*)(dst + 8) = *(const short8*)(src + 8);
    }
    __syncthreads();  // weights staged — only barrier before epilogue

    float ssum[8], sq[8];
#pragma unroll
    for (int t = 0; t < 8; ++t) { ssum[t] = 0.f; sq[t] = 0.f; }

    auto process = [&](const half8 (&afrag)[4], int m0) {
        f32x4 acc[8];
#pragma unroll
        for (int t = 0; t < 8; ++t) acc[t] = (f32x4){0.f, 0.f, 0.f, 0.f};
#pragma unroll
        for (int nc = 0; nc < 4; ++nc) {
            f32x4 macc[4];
#pragma unroll
            for (int nt = 0; nt < 4; ++nt) macc[nt] = (f32x4){0.f, 0.f, 0.f, 0.f};
#pragma unroll
            for (int kk4 = 0; kk4 < 4; ++kk4) {
                half8 a = afrag[kk4];
#pragma unroll
                for (int nt = 0; nt < 4; ++nt) {
                    half8 b = *(const half8*)&Bs1[(nc * 64 + nt * 16 + l16) * 136 + kk4 * 32 + quad * 8];
                    macc[nt] = __builtin_amdgcn_mfma_f32_16x16x32_f16(a, b, macc[nt], 0, 0, 0);
                }
            }
#pragma unroll
            for (int nt = 0; nt < 4; ++nt) {
                float bias = bias1v[nc][nt];
#pragma unroll
                for (int r = 0; r < 4; ++r) {
                    float v = fmaxf(macc[nt][r] + bias, 0.f);
                    half_t hv = (half_t)v;
                    Ms[(w * 16 + quad * 4 + r) * 72 + nt * 16 + l16] = *(ushort_t*)&hv;
                }
            }
            asm volatile("s_waitcnt lgkmcnt(0)" ::: "memory");
#pragma unroll
            for (int kk4 = 0; kk4 < 2; ++kk4) {
                half8 a = *(const half8*)&Ms[(w * 16 + l16) * 72 + kk4 * 32 + quad * 8];
#pragma unroll
                for (int t = 0; t < 8; ++t) {
                    half8 b = *(const half8*)&Bs2[((t >> 2) * 64 + (t & 3) * 16 + l16) * 264 + nc * 64 + kk4 * 32 + quad * 8];
                    acc[t] = __builtin_amdgcn_mfma_f32_16x16x32_f16(a, b, acc[t], 0, 0, 0);
                }
            }
        }
        // stats from acc (pre-transpose; identical values/order as before)
#pragma unroll
        for (int t = 0; t < 8; ++t) {
            float bias = bias2v[t];
#pragma unroll
            for (int r = 0; r < 4; ++r) {
                int row = m0 + w * 16 + quad * 4 + r;
                if (row < NN) {
                    float v = acc[t][r] + bias;
                    ssum[t] += v; sq[t] += v * v;
                }
            }
        }
        // coalesced h2 store: two 64-col passes via wave-private Ms rows
#pragma unroll
        for (int hf = 0; hf < 2; ++hf) {
#pragma unroll
            for (int tt = 0; tt < 4; ++tt) {
                int t = hf * 4 + tt;
                float bias = bias2v[t];
#pragma unroll
                for (int r = 0; r < 4; ++r) {
                    float v = acc[t][r] + bias;
                    half_t hv = (half_t)v;
                    Ms[(w * 16 + quad * 4 + r) * 72 + tt * 16 + l16] = *(ushort_t*)&hv;
                }
            }
            asm volatile("s_waitcnt lgkmcnt(0)" ::: "memory");
            int rrow = w * 16 + (lane >> 2);
            int ccol = (lane & 3) * 16;
            half8 o0 = *(const half8*)&Ms[rrow * 72 + ccol];
            half8 o1 = *(const half8*)&Ms[rrow * 72 + ccol + 8];
            int grow = m0 + rrow;
            if (grow < NN) {
                *(half8*)(h2 + (long long)grow * D + hf * 64 + ccol) = o0;
                *(half8*)(h2 + (long long)grow * D + hf * 64 + ccol + 8) = o1;
            }
            asm volatile("s_waitcnt lgkmcnt(0)" ::: "memory");  // WAR before next pass
        }
    };

    process(af0, tile0 * 128);
    if (has1) process(af1, tile1 * 128);

    // stats reduction: fold quads within wave, then one LDS pass per block
#pragma unroll
    for (int t = 0; t < 8; ++t) {
        ssum[t] += __shfl_xor(ssum[t], 16, 64);
        ssum[t] += __shfl_xor(ssum[t], 32, 64);
        sq[t]   += __shfl_xor(sq[t], 16, 64);
        sq[t]   += __shfl_xor(sq[t], 32, 64);
    }
    __syncthreads();                 // all waves done with Ms
    float* SSf = (float*)Ms;         // reuse Ms as 256-float scratch
    if (tid < 2 * D) SSf[tid] = 0.f;
    __syncthreads();
    if (quad == 0) {
#pragma unroll
        for (int t = 0; t < 8; ++t) {
            int col = (t >> 2) * 64 + (t & 3) * 16 + l16;
            atomicAdd(&SSf[col], ssum[t]);
            atomicAdd(&SSf[D + col], sq[t]);
        }
    }
    __syncthreads();
    if (tid < 2 * D) atomicAdd(&statsAdd[tid], SSf[tid]);
}

// final output: out = BN(h2) with gamma/beta of last layer (no relu), f32
__global__ void apply_k(const half_t* __restrict__ h2,
                        const float* __restrict__ statsPrev,
                        const void* __restrict__ gm, const void* __restrict__ bt,
                        const int* __restrict__ fl,
                        float* __restrict__ out) {
    __shared__ float norm_s[2 * D];
    int isf32 = *fl;
    int tid = threadIdx.x;
    if (tid < D) {
        float mu = statsPrev[tid] * (1.f / NN);
        float var = fmaxf(statsPrev[D + tid] * (1.f / NN) - mu * mu, 0.f);
        float rs = rsqrtf(var + 1e-5f);
        float sc = rs * loadF(gm, (long long)(NL - 1) * D + tid, isf32);
        float sh = loadF(bt, (long long)(NL - 1) * D + tid, isf32) - mu * sc;
        norm_s[tid] = sc;
        norm_s[D + tid] = sh;
    }
    __syncthreads();
    int idx = blockIdx.x * 256 + tid;  // over NN*64
    if (idx >= NN * 64) return;
    int fp = (idx & 63) * 2;
    unsigned hv = *(const unsigned*)(h2 + (long long)(idx >> 6) * D + fp);
    float v0 = fmaf((float)((const half_t*)&hv)[0], norm_s[fp], norm_s[D + fp]);
    float v1 = fmaf((float)((const half_t*)&hv)[1], norm_s[fp + 1], norm_s[D + fp + 1]);
    f32x2 o; o.x = v0; o.y = v1;
    *(f32x2*)(out + (long long)(idx >> 6) * D + fp) = o;
}

extern "C" void kernel_launch(void* const* d_in, const int* in_sizes, int n_in,
                              void* d_out, int out_size, void* d_ws, size_t ws_size,
                              hipStream_t stream) {
    const int* x     = (const int*)d_in[0];
    const int* ei    = (const int*)d_in[1];
    const int* ea    = (const int*)d_in[2];
    const void* atom = d_in[3];
    const void* chir = d_in[4];
    const void* hyb  = d_in[5];
    const void* e1   = d_in[6];
    const void* e2   = d_in[7];
    const void* W1   = d_in[8];
    const void* b1   = d_in[9];
    const void* W2   = d_in[10];
    const void* b2   = d_in[11];
    const void* gm   = d_in[12];
    const void* bt   = d_in[13];

    const size_t ND = (size_t)NN * D;

    char* base = (char*)d_ws;
    float* SP0     = (float*)base;            // stats buffer 0 (256 f32)
    float* SP1     = (float*)(base + 1024);   // stats buffer 1
    int*   flag    = (int*)(base + 2048);
    char*  p       = base + 4096;
    half_t* h2     = (half_t*)p;  p += ND * 2;
    half_t* w1t    = (half_t*)p;  p += (size_t)NL * 2 * D * D * 2;
    half_t* w2t    = (half_t*)p;  p += (size_t)NL * 2 * D * D * 2;
    float* combT   = (float*)p;   p += (size_t)NL * 24 * D * 4;
    int* csr       = (int*)p;     p += (size_t)NE * 4;
    int* row_start = (int*)p;     p += (size_t)(NN + 1) * 4 + 12;
    int* deg       = (int*)p;     p += (size_t)NN * 4;
    int* tmp       = (int*)p;     p += (size_t)NN * 4;
    int* next      = (int*)p;     p += (size_t)NN * 4;
    int* partial   = (int*)p;

    half_t* aggf = (half_t*)d_out;  // fp16 agg scratch; dead before apply_k

    const int N2_BLOCKS = (NN * 64 + 255) / 256;  // 12500
    const int NRM_BLOCKS = (NN * 16 + 255) / 256; // 3125
    const int E_BLOCKS  = (NE + 255) / 256;       // 2344
    const int N_BLOCKS  = (NN + 255) / 256;       // 196
    const int PW_BLOCKS = (2 * NL * 2 * D * D + NL * 24 * D + 255) / 256;

    setup_k<<<N_BLOCKS, 256, 0, stream>>>(atom, flag, deg, SP0);
    prepw_k<<<PW_BLOCKS, 256, 0, stream>>>(W1, W2, e1, e2, flag, w1t, w2t, combT);

    hist_k<<<E_BLOCKS, 256, 0, stream>>>(ei, deg);
    scan1_k<<<N_BLOCKS, 256, 0, stream>>>(deg, tmp, partial);
    scan2_k<<<1, 256, 0, stream>>>(partial, N_BLOCKS);
    scan3_k<<<N_BLOCKS, 256, 0, stream>>>(tmp, partial, deg, row_start, next);
    fill_k<<<E_BLOCKS, 256, 0, stream>>>(ei, ea, next, csr);

    embed_k<<<N2_BLOCKS, 256, 0, stream>>>(x, atom, chir, hyb, flag, h2);

    for (int l = 0; l < NL; ++l) {
        float* sPrev = ((l - 1) & 1) ? SP1 : SP0;   // stats of layer l-1 (l>0)
        float* sAdd  = (l & 1) ? SP1 : SP0;
        float* sZero = ((l + 1) & 1) ? SP1 : SP0;
        if (l > 0)
            norm_k<<<NRM_BLOCKS, 256, 0, stream>>>(h2, sPrev, gm, bt, flag, l - 1);
        aggr_k<<<AGG_BLOCKS, 256, 0, stream>>>(h2, row_start, csr, combT, l, aggf);
        mlp_k<<<MLP_BLOCKS, 512, 0, stream>>>(aggf, w1t, w2t, b1, b2, flag, l,
                                              h2, sAdd, sZero);
    }
    apply_k<<<N2_BLOCKS, 256, 0, stream>>>(h2, SP0, gm, bt, flag, (float*)d_out);
}